// Round 7
// baseline (151.677 us; speedup 1.0000x reference)
//
#include <hip/hip_runtime.h>
#include <hip/hip_bf16.h>
#include <cstdint>

// TT-linear: y[4096,4096] = x[4096,1024] @ W[1024,4096] + bias
// prep_wt: W^T reconstruction only (~2us). No xb: GEMM converts x f32->bf16
// in-register during A staging (cvt + swizzled ds_write_b128).
// tt_gemm: 128x128 tile, BK=64, single-buffer LDS (32KB, 4 blocks/CU),
//   waves 2x2 of 64x64, each 2x2 of mfma_f32_32x32x16_bf16 (half the MFMA
//   instr count of 16x16x32 at same FLOPs), XOR-swizzled LDS (0 conflicts).

typedef __bf16 bf16x8 __attribute__((ext_vector_type(8)));
typedef float f32x16 __attribute__((ext_vector_type(16)));

__device__ __forceinline__ void g2lds16(const void* g, void* l) {
    __builtin_amdgcn_global_load_lds(
        (const __attribute__((address_space(1))) void*)g,
        (__attribute__((address_space(3))) void*)l,
        16, 0, 0);
}

// ------------------------------------------------------------------ prep_wt
// 1024 blocks x 256 thr; 4 (m1,n1,m2,n2) groups per block (r3/r5-verified).
__global__ __launch_bounds__(256) void prep_wt(
    const float* __restrict__ c0, const float* __restrict__ c1,
    const float* __restrict__ c2, const float* __restrict__ c3,
    __bf16* __restrict__ wt) {
    __shared__ float t12[4][16];
    __shared__ float t123[4][512];
    __shared__ float c3s[512];
    const int t = threadIdx.x;
    #pragma unroll
    for (int i = t; i < 512; i += 256) c3s[i] = c3[i];
    const int s = t >> 6;
    const int lane = t & 63;
    const int g = blockIdx.x * 4 + s;
    const int m1 = g >> 9, n1 = (g >> 6) & 7, m2 = (g >> 3) & 7, n2 = g & 7;
    __syncthreads();
    if (lane < 16) {
        float sum = 0.f;
        #pragma unroll
        for (int r1 = 0; r1 < 16; ++r1)
            sum += c0[(m1 * 8 + n1) * 16 + r1] * c1[((r1 * 8 + m2) * 8 + n2) * 16 + lane];
        t12[s][lane] = sum;
    }
    __syncthreads();
    #pragma unroll
    for (int idx = lane; idx < 512; idx += 64) {
        const int m3 = idx >> 7, n3 = (idx >> 4) & 7, r3 = idx & 15;
        float sum = 0.f;
        #pragma unroll
        for (int r2 = 0; r2 < 16; ++r2)
            sum += t12[s][r2] * c2[((r2 * 4 + m3) * 8 + n3) * 16 + r3];
        t123[s][(m3 * 8 + n3) * 16 + r3] = sum;
    }
    __syncthreads();
    const int n3 = lane >> 3, n4 = lane & 7;
    const int n = ((n1 * 8 + n2) * 8 + n3) * 8 + n4;
    const int kbase = (m1 * 8 + m2) * 16;
    float v[16];
    #pragma unroll
    for (int e = 0; e < 16; ++e) v[e] = 0.f;
    #pragma unroll
    for (int m3 = 0; m3 < 4; ++m3) {
        #pragma unroll
        for (int r3 = 0; r3 < 16; ++r3) {
            const float tv = t123[s][(m3 * 8 + n3) * 16 + r3];
            #pragma unroll
            for (int m4 = 0; m4 < 4; ++m4)
                v[m3 * 4 + m4] += tv * c3s[(r3 * 4 + m4) * 8 + n4];
        }
    }
    bf16x8 lo, hi;
    #pragma unroll
    for (int e = 0; e < 8; ++e) { lo[e] = (__bf16)v[e]; hi[e] = (__bf16)v[8 + e]; }
    *(bf16x8*)(wt + (size_t)n * 1024 + kbase)     = lo;
    *(bf16x8*)(wt + (size_t)n * 1024 + kbase + 8) = hi;
}

// -------------------------------------------------------------- GEMM + bias
// C[4096,4096] f32 = x[4096,1024] f32(cvt bf16) @ wt[4096,1024]^T bf16 + bias
// A staged via f32 load + cvt + swizzled ds_write_b128; B via global_load_lds.
// Swizzle: physical 16B chunk = logical ^ (row&7); reader swz = (lane&31)&7.
__global__ __launch_bounds__(256) void tt_gemm(
    const float* __restrict__ X, const __bf16* __restrict__ B,
    const float* __restrict__ bias, float* __restrict__ C) {
    constexpr int K = 1024, N = 4096;
    __shared__ __bf16 sA[128 * 64];   // 16 KB
    __shared__ __bf16 sB[128 * 64];   // 16 KB
    const int t = threadIdx.x;
    const int lane = t & 63;
    const int wave = t >> 6;
    const int wm = (wave >> 1) * 64;
    const int wn = (wave & 1) * 64;
    const int bm = (blockIdx.x >> 5) * 128;   // row-major map (41 MB FETCH, r3)
    const int bn = (blockIdx.x & 31) * 128;
    const int l31 = lane & 31, l5 = lane >> 5;
    const int swz = l31 & 7;

    f32x16 acc[2][2] = {};

    for (int k0 = 0; k0 < K; k0 += 64) {
        __syncthreads();  // prior tile's LDS reads done before overwrite
        #pragma unroll
        for (int i = 0; i < 4; ++i) {       // B: DMA, swizzled source chunk
            const int c = t + i * 256;
            const int r = c >> 3;
            const int gc = (c & 7) ^ (r & 7);
            g2lds16(B + (size_t)(bn + r) * K + k0 + gc * 8, (char*)sB + (size_t)c * 16);
        }
        #pragma unroll
        for (int i = 0; i < 4; ++i) {       // A: f32 load + cvt + swizzled write
            const int c = t + i * 256;
            const int r = c >> 3;
            const int lc = c & 7;
            const float4* p = (const float4*)(X + (size_t)(bm + r) * K + k0 + lc * 8);
            float4 a0 = p[0], a1 = p[1];
            bf16x8 o;
            o[0] = (__bf16)a0.x; o[1] = (__bf16)a0.y; o[2] = (__bf16)a0.z; o[3] = (__bf16)a0.w;
            o[4] = (__bf16)a1.x; o[5] = (__bf16)a1.y; o[6] = (__bf16)a1.z; o[7] = (__bf16)a1.w;
            const int pc = lc ^ (r & 7);
            *(bf16x8*)((char*)sA + (size_t)(r * 8 + pc) * 16) = o;
        }
        asm volatile("s_waitcnt vmcnt(0)" ::: "memory");
        __syncthreads();
        #pragma unroll
        for (int kk = 0; kk < 4; ++kk) {    // K=16 per step
            const int coff = ((2 * kk + l5) ^ swz) * 16;  // swizzled byte offset
            bf16x8 af[2], bfr[2];
            #pragma unroll
            for (int mi = 0; mi < 2; ++mi)
                af[mi] = *(const bf16x8*)((const char*)sA + (size_t)(wm + mi * 32 + l31) * 128 + coff);
            #pragma unroll
            for (int ni = 0; ni < 2; ++ni)
                bfr[ni] = *(const bf16x8*)((const char*)sB + (size_t)(wn + ni * 32 + l31) * 128 + coff);
            #pragma unroll
            for (int mi = 0; mi < 2; ++mi)
                #pragma unroll
                for (int ni = 0; ni < 2; ++ni)
                    acc[mi][ni] = __builtin_amdgcn_mfma_f32_32x32x16_bf16(
                        af[mi], bfr[ni], acc[mi][ni], 0, 0, 0);
        }
    }

    // epilogue: 32x32 C/D layout col=lane&31, row=(reg&3)+8*(reg>>2)+4*(lane>>5)
    #pragma unroll
    for (int ni = 0; ni < 2; ++ni) {
        const int col = bn + wn + ni * 32 + l31;
        const float bv = bias[col];
        #pragma unroll
        for (int mi = 0; mi < 2; ++mi) {
            const int row0 = bm + wm + mi * 32 + 4 * l5;
            const f32x16 v = acc[mi][ni];
            #pragma unroll
            for (int r = 0; r < 16; ++r) {
                const int row = row0 + (r & 3) + 8 * (r >> 2);
                C[(size_t)row * N + col] = v[r] + bv;
            }
        }
    }
}

extern "C" void kernel_launch(void* const* d_in, const int* in_sizes, int n_in,
                              void* d_out, int out_size, void* d_ws, size_t ws_size,
                              hipStream_t stream) {
    const float* x    = (const float*)d_in[0];
    const float* c0   = (const float*)d_in[1];
    const float* c1   = (const float*)d_in[2];
    const float* c2   = (const float*)d_in[3];
    const float* c3   = (const float*)d_in[4];
    const float* bias = (const float*)d_in[5];
    float* out = (float*)d_out;

    __bf16* wt = (__bf16*)d_ws;                    // 4096*1024 bf16 = 8.39 MB

    prep_wt<<<1024, 256, 0, stream>>>(c0, c1, c2, c3, wt);
    tt_gemm<<<1024, 256, 0, stream>>>(x, wt, bias, out);
}